// Round 3
// baseline (344.679 us; speedup 1.0000x reference)
//
#include <hip/hip_runtime.h>
#include <hip/hip_bf16.h>

#define NB 16
#define TT 2048
#define CC 384

typedef short bf16x8 __attribute__((ext_vector_type(8)));
typedef float f32x4 __attribute__((ext_vector_type(4)));

static __device__ __forceinline__ short f2bf(float f) {
  union { __hip_bfloat16 h; short s; } u;
  u.h = __float2bfloat16(f);
  return u.s;
}

// C^-0.5 * log2(e): folded into Q at projection time (attn works in exp2 domain)
#define QSC (0.051031036307982884f * 1.4426950408889634f)

// ---------------------------------------------------------------------------
// W[3] (fp32 [C][H]) -> Wbt (bf16 [3][n=H][k=C])  (transposed for LDS staging)
// ---------------------------------------------------------------------------
__global__ __launch_bounds__(384)
void conv_wt(const float* __restrict__ Wq, const float* __restrict__ Wk,
             const float* __restrict__ Wv, short* __restrict__ Wbt) {
  const int w = blockIdx.x / CC;
  const int n = blockIdx.x % CC;
  const int k = threadIdx.x;
  const float* W = (w == 0) ? Wq : (w == 1) ? Wk : Wv;
  Wbt[((size_t)w * CC + n) * CC + k] = f2bf(W[(size_t)k * CC + n]);
}

// ---------------------------------------------------------------------------
// Fused QKV projection GEMM: [32768 x 384](fp32 x, converted in-reg) x
// [384 x 1152] bf16 MFMA, register-prefetch pipelined.
// n-tiles 0-2 -> Q (pre-scaled by QSC), 3-5 -> K, 6-8 -> V transposed to
// Vt[b][d][t] via LDS transpose epilogue.
// ---------------------------------------------------------------------------
__global__ __launch_bounds__(256, 3)
void proj_gemm(const float* __restrict__ x, const short* __restrict__ Wbt,
               short* __restrict__ Q, short* __restrict__ K,
               short* __restrict__ Vt) {
  __shared__ char smem[34816];           // staging (2x10240) U epilogue (34816)
  short* As = (short*)smem;              // [128][40] shorts (32 data + 8 pad)
  short* Bs = (short*)(smem + 10240);    // [128][40]
  short* Es = (short*)smem;              // epilogue [128][136]

  const int mt = blockIdx.x & 255;
  const int nt = blockIdx.x >> 8;        // 0..8
  const int wsel = nt / 3;               // 0=Q,1=K,2=V
  const int nc0 = (nt % 3) * 128;
  const int tid = threadIdx.x;
  const int wave = tid >> 6, lane = tid & 63;
  const int l15 = lane & 15, quad = lane >> 4;
  const int wm = (wave & 1) * 64, wn = (wave >> 1) * 64;

  const float* Ab = x + (size_t)mt * 128 * CC;
  const short* Bb = Wbt + ((size_t)wsel * CC + nc0) * CC;

  f32x4 acc[16];
  #pragma unroll
  for (int i = 0; i < 16; ++i) acc[i] = f32x4{0.f, 0.f, 0.f, 0.f};

  // prefetch registers
  float4 ra[4];
  bf16x8 rb[2];
  #pragma unroll
  for (int c = 0; c < 4; ++c) {
    const int ci = c * 256 + tid;        // float4-chunk, 0..1023
    ra[c] = *(const float4*)(Ab + (size_t)(ci >> 3) * CC + (ci & 7) * 4);
  }
  #pragma unroll
  for (int c = 0; c < 2; ++c) {
    const int ci = c * 256 + tid;        // 16B-chunk, 0..511
    rb[c] = *(const bf16x8*)(Bb + (size_t)(ci >> 2) * CC + (ci & 3) * 8);
  }

  for (int kt = 0; kt < 12; ++kt) {
    __syncthreads();
    #pragma unroll
    for (int c = 0; c < 4; ++c) {
      const int ci = c * 256 + tid;
      short4 s4;
      s4.x = f2bf(ra[c].x); s4.y = f2bf(ra[c].y);
      s4.z = f2bf(ra[c].z); s4.w = f2bf(ra[c].w);
      *(short4*)((char*)As + (ci >> 3) * 80 + (ci & 7) * 8) = s4;
    }
    #pragma unroll
    for (int c = 0; c < 2; ++c) {
      const int ci = c * 256 + tid;
      *(bf16x8*)((char*)Bs + (ci >> 2) * 80 + (ci & 3) * 16) = rb[c];
    }
    __syncthreads();
    if (kt < 11) {
      const int k0 = (kt + 1) * 32;
      #pragma unroll
      for (int c = 0; c < 4; ++c) {
        const int ci = c * 256 + tid;
        ra[c] = *(const float4*)(Ab + (size_t)(ci >> 3) * CC + k0 + (ci & 7) * 4);
      }
      #pragma unroll
      for (int c = 0; c < 2; ++c) {
        const int ci = c * 256 + tid;
        rb[c] = *(const bf16x8*)(Bb + (size_t)(ci >> 2) * CC + k0 + (ci & 3) * 8);
      }
    }
    bf16x8 af[4], bf[4];
    #pragma unroll
    for (int i = 0; i < 4; ++i) {
      af[i] = *(const bf16x8*)((char*)As + (wm + i * 16 + l15) * 80 + quad * 16);
      bf[i] = *(const bf16x8*)((char*)Bs + (wn + i * 16 + l15) * 80 + quad * 16);
    }
    #pragma unroll
    for (int i = 0; i < 4; ++i)
      #pragma unroll
      for (int j = 0; j < 4; ++j)
        acc[i * 4 + j] =
            __builtin_amdgcn_mfma_f32_16x16x32_bf16(af[i], bf[j], acc[i * 4 + j], 0, 0, 0);
  }

  if (nt < 6) {
    short* O = (nt < 3) ? Q : K;
    const float sc = (nt < 3) ? QSC : 1.0f;
    #pragma unroll
    for (int i = 0; i < 4; ++i)
      #pragma unroll
      for (int j = 0; j < 4; ++j) {
        const f32x4 a = acc[i * 4 + j];
        const int r0 = mt * 128 + wm + i * 16 + quad * 4;
        const int c = nc0 + wn + j * 16 + l15;
        #pragma unroll
        for (int r = 0; r < 4; ++r) O[(size_t)(r0 + r) * CC + c] = f2bf(a[r] * sc);
      }
  } else {
    __syncthreads();                     // done with As/Bs; reuse as Es
    #pragma unroll
    for (int i = 0; i < 4; ++i)
      #pragma unroll
      for (int j = 0; j < 4; ++j) {
        const f32x4 a = acc[i * 4 + j];
        const int dl = wn + j * 16 + l15;       // local col (d)
        const int ml = wm + i * 16 + quad * 4;  // local row (t)
        short4 p4;
        p4.x = f2bf(a[0]); p4.y = f2bf(a[1]); p4.z = f2bf(a[2]); p4.w = f2bf(a[3]);
        *(short4*)(Es + (size_t)dl * 136 + ml) = p4;
      }
    __syncthreads();
    const int d0 = (nt - 6) * 128;
    const int b = mt >> 4, t0 = (mt & 15) * 128;
    const int dr = tid >> 1, hf = tid & 1;
    const short* src = Es + (size_t)dr * 136 + hf * 64;
    short* dst = Vt + ((size_t)b * CC + d0 + dr) * TT + t0 + hf * 64;
    #pragma unroll
    for (int c = 0; c < 8; ++c)
      *(bf16x8*)(dst + c * 8) = *(const bf16x8*)(src + c * 8);
  }
}

// ---------------------------------------------------------------------------
// Flash attention, causal. Block = 64 queries / 4 waves, 32-key chunks.
// NEW vs prev round:
//  * Balanced sequential schedule: grid 256 (1 block/CU), block (j, b)
//    processes q-tile (31-j) THEN q-tile j -> every block = exactly 68
//    chunk-iterations. No idle CUs, no solo tail (was: 12% avg occupancy,
//    makespan CU 96 chunks half-solo).
//  * Full LDS double-buffering of K and V (103424 B static, 1 block/CU owns
//    the whole 160K LDS): ONE vmcnt wait + 2 barriers per chunk (was 2 waits
//    + 4 barriers), K and V of a chunk co-available, stage issued 2 chunks
//    ahead so landing hides under a full chunk of compute.
//  * In-loop stage predicated (block-uniform) -> no dummy loads; last
//    iteration waits vmcnt(0).
// ---------------------------------------------------------------------------
__global__ __launch_bounds__(256, 1)
void attn_kernel(const short* __restrict__ Q, const short* __restrict__ K,
                 const short* __restrict__ Vt, float* __restrict__ out) {
  __shared__ char sm[103424];
  // [0,24576)       K buf0   [32 keys][48 slots^row 16B]
  // [24576,49152)   K buf1
  // [49152,73728)   V buf0   [384 d][4 slots rot 16B]
  // [73728,98304)   V buf1
  // [98304,103424)  Ps       [4 waves][16][40] shorts

  const int blk = blockIdx.x;
  const int jj = blk >> 4;                  // 0..15
  const int b  = blk & 15;                  // XCD = blk%8 = b%8
  const int tid = threadIdx.x;
  const int wave = tid >> 6, lane = tid & 63;
  const int l15 = lane & 15, quad = lane >> 4;
  short* pw = (short*)(sm + 98304) + wave * 640;

  bf16x8 onesf;
  #pragma unroll
  for (int i = 0; i < 8; ++i) onesf[i] = (short)0x3F80;   // bf16 1.0

  // per-lane pre-swizzled global source offsets for the 6 K and 6 V issues
  int koff[6], voff[6];
  #pragma unroll
  for (int j = 0; j < 6; ++j) {
    const int lin = wave * 6144 + j * 1024 + lane * 16;  // linear LDS byte
    const int kr = lin / 768;                            // K row (768 B rows)
    const int ksl = (lin - kr * 768) >> 4;               // K 16B slot
    koff[j] = kr * 768 + ((ksl ^ (kr & 7)) << 4);        // inverse XOR swizzle
    const int vr = lin >> 6;                             // V row (64 B rows)
    const int vsl = (lin >> 4) & 3;
    voff[j] = vr * 4096 + (((vsl - (vr >> 2)) & 3) << 4);  // inverse rotate
  }
  const char* kbB = (const char*)(K + (size_t)b * TT * CC);
  const char* vtB = (const char*)(Vt + (size_t)b * CC * TT);

  #pragma unroll 1
  for (int half = 0; half < 2; ++half) {
    const int qt = half ? jj : (31 - jj);
    const int q0 = qt * 64 + wave * 16;
    const int nchunk = qt * 2 + 2;

    // Q fragments resident in registers (Q pre-scaled by QSC)
    bf16x8 qf[12];
    const short* qp = Q + ((size_t)b * TT + q0 + l15) * CC + quad * 8;
    #pragma unroll
    for (int ks = 0; ks < 12; ++ks) qf[ks] = *(const bf16x8*)(qp + ks * 32);
    // drain q loads (and previous tile's output stores) -> clean vmcnt base
    asm volatile("s_waitcnt vmcnt(0)" ::: "memory");

    f32x4 o[24];
    #pragma unroll
    for (int n = 0; n < 24; ++n) o[n] = f32x4{0.f, 0.f, 0.f, 0.f};
    f32x4 lsum = f32x4{0.f, 0.f, 0.f, 0.f};
    float m[4];
    #pragma unroll
    for (int r = 0; r < 4; ++r) m[r] = -INFINITY;

    // prologue: stage chunk 0 -> buf0, chunk 1 -> buf1 (12 issues each/wave)
    #pragma unroll
    for (int pc = 0; pc < 2; ++pc) {
      char* KsW = sm + pc * 24576 + wave * 6144;
      char* VsW = sm + 49152 + pc * 24576 + wave * 6144;
      const size_t kby = (size_t)pc * 24576;   // 32 keys * 768 B
      const size_t vby = (size_t)pc * 64;      // 32 keys * 2 B
      #pragma unroll
      for (int j = 0; j < 6; ++j)
        __builtin_amdgcn_global_load_lds(
            (const __attribute__((address_space(1))) void*)(kbB + kby + koff[j]),
            (__attribute__((address_space(3))) void*)(KsW + j * 1024), 16, 0, 0);
      #pragma unroll
      for (int j = 0; j < 6; ++j)
        __builtin_amdgcn_global_load_lds(
            (const __attribute__((address_space(1))) void*)(vtB + vby + voff[j]),
            (__attribute__((address_space(3))) void*)(VsW + j * 1024), 16, 0, 0);
    }

    for (int kc = 0; kc < nchunk; ++kc) {
      const int k0 = kc * 32;
      const int kb = kc & 1;
      // buf[kb] (staged 2 chunks ago / prologue) must be landed
      if (kc + 1 == nchunk) {
        asm volatile("s_waitcnt vmcnt(0)" ::: "memory");
      } else {
        asm volatile("s_waitcnt vmcnt(12)" ::: "memory");
      }
      __builtin_amdgcn_s_barrier();
      __builtin_amdgcn_sched_barrier(0);

      const bool active = (k0 <= q0 + 15);
      if (active) {
        const char* Ksb = sm + kb * 24576;
        const char* Vsb = sm + 49152 + kb * 24576;
        // ---- S = Q K^T (16 q x 32 keys), log2 domain via Q scaling
        f32x4 s0 = f32x4{0.f, 0.f, 0.f, 0.f};
        f32x4 s1 = f32x4{0.f, 0.f, 0.f, 0.f};
        #pragma unroll
        for (int ks = 0; ks < 12; ++ks) {
          const int sl = (ks * 4 + quad) ^ (l15 & 7);
          const bf16x8 b0 = *(const bf16x8*)(Ksb + l15 * 768 + (sl << 4));
          const bf16x8 b1 = *(const bf16x8*)(Ksb + (16 + l15) * 768 + (sl << 4));
          s0 = __builtin_amdgcn_mfma_f32_16x16x32_bf16(qf[ks], b0, s0, 0, 0, 0);
          s1 = __builtin_amdgcn_mfma_f32_16x16x32_bf16(qf[ks], b1, s1, 0, 0, 0);
        }
        // ---- causal mask + row max
        const bool domask = (k0 + 31 > q0);
        float mx[4];
        #pragma unroll
        for (int r = 0; r < 4; ++r) {
          float a = s0[r], c = s1[r];
          if (domask) {
            const int qg = q0 + quad * 4 + r;
            if (k0 + l15 > qg)      a = -INFINITY;
            if (k0 + 16 + l15 > qg) c = -INFINITY;
          }
          s0[r] = a; s1[r] = c;
          float v = fmaxf(a, c);
          v = fmaxf(v, __shfl_xor(v, 1));
          v = fmaxf(v, __shfl_xor(v, 2));
          v = fmaxf(v, __shfl_xor(v, 4));
          v = fmaxf(v, __shfl_xor(v, 8));
          mx[r] = v;
        }
        // ---- online softmax update (exp2 domain)
        float alpha[4];
        #pragma unroll
        for (int r = 0; r < 4; ++r) {
          const float mn = fmaxf(m[r], mx[r]);
          alpha[r] = exp2f(m[r] - mn);
          m[r] = mn;
          s0[r] = exp2f(s0[r] - mn);
          s1[r] = exp2f(s1[r] - mn);
        }
        const bool need = (alpha[0] < 1.f) | (alpha[1] < 1.f) |
                          (alpha[2] < 1.f) | (alpha[3] < 1.f);
        if (__any(need)) {
          #pragma unroll
          for (int r = 0; r < 4; ++r) lsum[r] *= alpha[r];
          #pragma unroll
          for (int n = 0; n < 24; ++n) {
            #pragma unroll
            for (int r = 0; r < 4; ++r) o[n][r] *= alpha[r];
          }
        }
        // ---- P: C-layout -> A-layout via wave-private LDS
        #pragma unroll
        for (int r = 0; r < 4; ++r) {
          pw[(quad * 4 + r) * 40 + l15]      = f2bf(s0[r]);
          pw[(quad * 4 + r) * 40 + 16 + l15] = f2bf(s1[r]);
        }
        const bf16x8 pf = *(const bf16x8*)(pw + l15 * 40 + quad * 8);
        // ---- l += P . 1
        lsum = __builtin_amdgcn_mfma_f32_16x16x32_bf16(pf, onesf, lsum, 0, 0, 0);
        // ---- O += P V
        #pragma unroll
        for (int n = 0; n < 24; ++n) {
          const int vrow = n * 16 + l15;
          const bf16x8 vf = *(const bf16x8*)(Vsb + vrow * 64 + (((quad + (vrow >> 2)) & 3) << 4));
          o[n] = __builtin_amdgcn_mfma_f32_16x16x32_bf16(pf, vf, o[n], 0, 0, 0);
        }
      }
      __builtin_amdgcn_sched_barrier(0);
      __builtin_amdgcn_s_barrier();          // all waves done reading buf[kb]
      // ---- stage chunk kc+2 into buf[kb] (block-uniform predicate)
      if (kc + 2 < nchunk) {
        char* KsW = sm + kb * 24576 + wave * 6144;
        char* VsW = sm + 49152 + kb * 24576 + wave * 6144;
        const size_t kby = (size_t)(kc + 2) * 24576;
        const size_t vby = (size_t)(kc + 2) * 64;
        #pragma unroll
        for (int j = 0; j < 6; ++j)
          __builtin_amdgcn_global_load_lds(
              (const __attribute__((address_space(1))) void*)(kbB + kby + koff[j]),
              (__attribute__((address_space(3))) void*)(KsW + j * 1024), 16, 0, 0);
        #pragma unroll
        for (int j = 0; j < 6; ++j)
          __builtin_amdgcn_global_load_lds(
              (const __attribute__((address_space(1))) void*)(vtB + vby + voff[j]),
              (__attribute__((address_space(3))) void*)(VsW + j * 1024), 16, 0, 0);
      }
    }

    // ---- epilogue for this tile
    float linv[4];
    #pragma unroll
    for (int r = 0; r < 4; ++r) linv[r] = 1.f / lsum[r];
    float* ob = out + ((size_t)b * TT + q0) * CC;
    #pragma unroll
    for (int n = 0; n < 24; ++n) {
      #pragma unroll
      for (int r = 0; r < 4; ++r) {
        ob[(size_t)(quad * 4 + r) * CC + n * 16 + l15] = o[n][r] * linv[r];
      }
    }
  }
}

extern "C" void kernel_launch(void* const* d_in, const int* in_sizes, int n_in,
                              void* d_out, int out_size, void* d_ws, size_t ws_size,
                              hipStream_t stream) {
  const float* x  = (const float*)d_in[0];
  const float* Wq = (const float*)d_in[1];
  const float* Wk = (const float*)d_in[2];
  const float* Wv = (const float*)d_in[3];
  float* out = (float*)d_out;

  const size_t QS = (size_t)NB * TT * CC;     // 12.58M elems
  short* Qs = (short*)d_ws;
  short* Ks = Qs + QS;
  short* Vt = Ks + QS;                        // ws: 75.5 MB

  // bf16 W^T staging lives in d_out (50 MB fp32) until attn overwrites it
  short* Wbt = (short*)d_out;                 // 0.9 MB

  hipLaunchKernelGGL(conv_wt, dim3(3 * CC), dim3(CC), 0, stream, Wq, Wk, Wv, Wbt);
  hipLaunchKernelGGL(proj_gemm, dim3(256 * 9), dim3(256), 0, stream,
                     x, Wbt, Qs, Ks, Vt);
  hipLaunchKernelGGL(attn_kernel, dim3(NB * TT / 128), dim3(256), 0, stream,
                     Qs, Ks, Vt, out);
}

// Round 4
// 301.855 us; speedup vs baseline: 1.1419x; 1.1419x over previous
//
#include <hip/hip_runtime.h>
#include <hip/hip_bf16.h>

#define NB 16
#define TT 2048
#define CC 384

typedef short bf16x8 __attribute__((ext_vector_type(8)));
typedef float f32x4 __attribute__((ext_vector_type(4)));

static __device__ __forceinline__ short f2bf(float f) {
  union { __hip_bfloat16 h; short s; } u;
  u.h = __float2bfloat16(f);
  return u.s;
}

// C^-0.5 * log2(e): folded into Q at projection time (attn works in exp2 domain)
#define QSC (0.051031036307982884f * 1.4426950408889634f)

// ---------------------------------------------------------------------------
// W[3] (fp32 [C][H]) -> Wbt (bf16 [3][n=H][k=C])  (transposed for LDS staging)
// ---------------------------------------------------------------------------
__global__ __launch_bounds__(384)
void conv_wt(const float* __restrict__ Wq, const float* __restrict__ Wk,
             const float* __restrict__ Wv, short* __restrict__ Wbt) {
  const int w = blockIdx.x / CC;
  const int n = blockIdx.x % CC;
  const int k = threadIdx.x;
  const float* W = (w == 0) ? Wq : (w == 1) ? Wk : Wv;
  Wbt[((size_t)w * CC + n) * CC + k] = f2bf(W[(size_t)k * CC + n]);
}

// ---------------------------------------------------------------------------
// x (fp32 [B*T*C]) -> xb (bf16), one pass. Removes the per-kt f2bf VALU work
// from proj_gemm's K-loop.
// ---------------------------------------------------------------------------
__global__ __launch_bounds__(256)
void xconv(const float* __restrict__ x, short* __restrict__ xb) {
  const int i = (blockIdx.x * 256 + threadIdx.x) * 8;
  const float4 a = *(const float4*)(x + i);
  const float4 c = *(const float4*)(x + i + 4);
  bf16x8 r;
  r[0] = f2bf(a.x); r[1] = f2bf(a.y); r[2] = f2bf(a.z); r[3] = f2bf(a.w);
  r[4] = f2bf(c.x); r[5] = f2bf(c.y); r[6] = f2bf(c.z); r[7] = f2bf(c.w);
  *(bf16x8*)(xb + i) = r;
}

// ---------------------------------------------------------------------------
// Fused QKV projection GEMM: [32768 x 384] bf16 x [384 x 1152] bf16.
// NEW: A and B staged via global_load_lds (16B async), double-buffered,
// counted vmcnt(4) so staging spans the MFMA phase. LDS rows 64B linear,
// XOR swizzle s^=((r>>1)&3) applied on the pre-swizzled GLOBAL source and
// on the LDS read -> 2-way (free) bank access. No in-loop cvt/ds_write.
// n-tiles 0-2 -> Q (pre-scaled by QSC), 3-5 -> K, 6-8 -> V transposed to
// Vt[b][d][t] via LDS transpose epilogue.
// ---------------------------------------------------------------------------
__global__ __launch_bounds__(256, 3)
void proj_gemm(const short* __restrict__ xb, const short* __restrict__ Wbt,
               short* __restrict__ Q, short* __restrict__ K,
               short* __restrict__ Vt) {
  __shared__ char smem[34816];
  // staging: A0 [0,8K) A1 [8K,16K) B0 [16K,24K) B1 [24K,32K); Es reuses all.
  short* Es = (short*)smem;              // epilogue [128][136]

  const int mt = blockIdx.x & 255;
  const int nt = blockIdx.x >> 8;        // 0..8
  const int wsel = nt / 3;               // 0=Q,1=K,2=V
  const int nc0 = (nt % 3) * 128;
  const int tid = threadIdx.x;
  const int wave = tid >> 6, lane = tid & 63;
  const int l15 = lane & 15, quad = lane >> 4;
  const int wm = (wave & 1) * 64, wn = (wave >> 1) * 64;

  const short* Ab = xb + (size_t)mt * 128 * CC;
  const short* Bb = Wbt + ((size_t)wsel * CC + nc0) * CC;

  // per-lane pre-swizzled source offsets (elements) for the 2 issues/wave
  int aoff[2];
  #pragma unroll
  for (int j = 0; j < 2; ++j) {
    const int lin = wave * 2048 + j * 1024 + lane * 16;  // byte in 8K tile
    const int r = lin >> 6;                              // row (64B rows)
    const int s = (lin >> 4) & 3;                        // 16B slot
    aoff[j] = r * CC + ((s ^ ((r >> 1) & 3)) * 8);       // inverse swizzle
  }
  char* AW = smem + wave * 2048;
  char* BW = smem + 16384 + wave * 2048;

  f32x4 acc[16];
  #pragma unroll
  for (int i = 0; i < 16; ++i) acc[i] = f32x4{0.f, 0.f, 0.f, 0.f};

  // prologue: stage kt 0 -> buf0, kt 1 -> buf1 (4 issues/wave per kt)
  #pragma unroll
  for (int pc = 0; pc < 2; ++pc) {
    #pragma unroll
    for (int j = 0; j < 2; ++j)
      __builtin_amdgcn_global_load_lds(
          (const __attribute__((address_space(1))) void*)(Ab + pc * 32 + aoff[j]),
          (__attribute__((address_space(3))) void*)(AW + pc * 8192 + j * 1024), 16, 0, 0);
    #pragma unroll
    for (int j = 0; j < 2; ++j)
      __builtin_amdgcn_global_load_lds(
          (const __attribute__((address_space(1))) void*)(Bb + pc * 32 + aoff[j]),
          (__attribute__((address_space(3))) void*)(BW + pc * 8192 + j * 1024), 16, 0, 0);
  }

  for (int kt = 0; kt < 12; ++kt) {
    const int kb = kt & 1;
    if (kt == 11) {
      asm volatile("s_waitcnt vmcnt(0)" ::: "memory");
    } else {
      asm volatile("s_waitcnt vmcnt(4)" ::: "memory");
    }
    __builtin_amdgcn_s_barrier();
    __builtin_amdgcn_sched_barrier(0);

    const char* As = smem + kb * 8192;
    const char* Bs = smem + 16384 + kb * 8192;
    bf16x8 af[4], bf[4];
    #pragma unroll
    for (int i = 0; i < 4; ++i) {
      const int ar = wm + i * 16 + l15;
      const int br = wn + i * 16 + l15;
      af[i] = *(const bf16x8*)(As + ar * 64 + ((quad ^ ((ar >> 1) & 3)) << 4));
      bf[i] = *(const bf16x8*)(Bs + br * 64 + ((quad ^ ((br >> 1) & 3)) << 4));
    }
    #pragma unroll
    for (int i = 0; i < 4; ++i)
      #pragma unroll
      for (int j = 0; j < 4; ++j)
        acc[i * 4 + j] =
            __builtin_amdgcn_mfma_f32_16x16x32_bf16(af[i], bf[j], acc[i * 4 + j], 0, 0, 0);

    __builtin_amdgcn_sched_barrier(0);
    __builtin_amdgcn_s_barrier();
    if (kt + 2 < 12) {
      const int k0 = (kt + 2) * 32;
      #pragma unroll
      for (int j = 0; j < 2; ++j)
        __builtin_amdgcn_global_load_lds(
            (const __attribute__((address_space(1))) void*)(Ab + k0 + aoff[j]),
            (__attribute__((address_space(3))) void*)(AW + kb * 8192 + j * 1024), 16, 0, 0);
      #pragma unroll
      for (int j = 0; j < 2; ++j)
        __builtin_amdgcn_global_load_lds(
            (const __attribute__((address_space(1))) void*)(Bb + k0 + aoff[j]),
            (__attribute__((address_space(3))) void*)(BW + kb * 8192 + j * 1024), 16, 0, 0);
    }
  }

  if (nt < 6) {
    short* O = (nt < 3) ? Q : K;
    const float sc = (nt < 3) ? QSC : 1.0f;
    #pragma unroll
    for (int i = 0; i < 4; ++i)
      #pragma unroll
      for (int j = 0; j < 4; ++j) {
        const f32x4 a = acc[i * 4 + j];
        const int r0 = mt * 128 + wm + i * 16 + quad * 4;
        const int c = nc0 + wn + j * 16 + l15;
        #pragma unroll
        for (int r = 0; r < 4; ++r) O[(size_t)(r0 + r) * CC + c] = f2bf(a[r] * sc);
      }
  } else {
    __syncthreads();                     // done with staging; reuse as Es
    #pragma unroll
    for (int i = 0; i < 4; ++i)
      #pragma unroll
      for (int j = 0; j < 4; ++j) {
        const f32x4 a = acc[i * 4 + j];
        const int dl = wn + j * 16 + l15;       // local col (d)
        const int ml = wm + i * 16 + quad * 4;  // local row (t)
        short4 p4;
        p4.x = f2bf(a[0]); p4.y = f2bf(a[1]); p4.z = f2bf(a[2]); p4.w = f2bf(a[3]);
        *(short4*)(Es + (size_t)dl * 136 + ml) = p4;
      }
    __syncthreads();
    const int d0 = (nt - 6) * 128;
    const int b = mt >> 4, t0 = (mt & 15) * 128;
    const int dr = tid >> 1, hf = tid & 1;
    const short* src = Es + (size_t)dr * 136 + hf * 64;
    short* dst = Vt + ((size_t)b * CC + d0 + dr) * TT + t0 + hf * 64;
    #pragma unroll
    for (int c = 0; c < 8; ++c)
      *(bf16x8*)(dst + c * 8) = *(const bf16x8*)(src + c * 8);
  }
}

// ===========================================================================
// Flash attention, causal, 64q/4-wave blocks, 32-key chunks, async
// global_load_lds double-buffered staging (round-2 proven core).
//
// attn_split (new): balanced pair schedule, grid 512 = 2 blocks/CU, EVERY
// block exactly 33 chunks -> 2-way TLP with zero tail:
//   pair (b,j): H = 31-j (64-2j chunks), L = j (2j+2 chunks)
//   role A: [L full -> final] then [H keys 0..32*(31-2j) -> partial A]
//   role B: [H keys 32*(31-2j)..  -> partial B (incl. diagonal)]
// Partial A (unnormalized O, f32) parked IN PLACE in out[H rows]; partial B
// O in ws; m/l both in ws; combine kernel merges. Falls back to attn_plain
// (round-2 exact) when ws_size is too small for partials.
// ===========================================================================

#define ATTN_PRELUDE                                                          \
  __shared__ char sm[54272];                                                  \
  char* KsS = sm;                                                             \
  char* VsS = sm + 24576;                                                     \
  const int tid = threadIdx.x;                                                \
  const int wave = tid >> 6, lane = tid & 63;                                 \
  const int l15 = lane & 15, quad = lane >> 4;                                \
  short* pw = (short*)(sm + 49152) + wave * 640;                              \
  bf16x8 onesf;                                                               \
  _Pragma("unroll")                                                           \
  for (int i = 0; i < 8; ++i) onesf[i] = (short)0x3F80;                       \
  int koff[6], voff[6];                                                       \
  _Pragma("unroll")                                                           \
  for (int j = 0; j < 6; ++j) {                                               \
    const int lin = wave * 6144 + j * 1024 + lane * 16;                       \
    const int kr = lin / 768;                                                 \
    const int ksl = (lin - kr * 768) >> 4;                                    \
    koff[j] = kr * 768 + ((ksl ^ (kr & 7)) << 4);                             \
    const int vr = lin >> 6;                                                  \
    const int vsl = (lin >> 4) & 3;                                           \
    voff[j] = vr * 4096 + (((vsl - (vr >> 2)) & 3) << 4);                     \
  }                                                                           \
  char* KsW = KsS + wave * 6144;                                              \
  char* VsW = VsS + wave * 6144;

#define STAGE_CHUNK(ck)                                                       \
  do {                                                                        \
    const size_t kby_ = (size_t)(ck) * 24576;                                 \
    const size_t vby_ = (size_t)(ck) * 64;                                    \
    _Pragma("unroll")                                                         \
    for (int j = 0; j < 6; ++j)                                               \
      __builtin_amdgcn_global_load_lds(                                       \
          (const __attribute__((address_space(1))) void*)(kbB + kby_ + koff[j]), \
          (__attribute__((address_space(3))) void*)(KsW + j * 1024), 16, 0, 0);  \
    _Pragma("unroll")                                                         \
    for (int j = 0; j < 6; ++j)                                               \
      __builtin_amdgcn_global_load_lds(                                       \
          (const __attribute__((address_space(1))) void*)(vtB + vby_ + voff[j]), \
          (__attribute__((address_space(3))) void*)(VsW + j * 1024), 16, 0, 0);  \
  } while (0)

// chunk-loop body shared by both kernels (expects qt,q0,c0,c1 set; acc in
// o/lsum/m). Uses per-phase buffers indexed (kc-c0)&1 via base offset swap.
#define CHUNK_LOOP(C0, C1)                                                    \
  for (int kc = (C0); kc < (C1); ++kc) {                                      \
    const int k0 = kc * 32;                                                   \
    const int kb = (kc - (C0)) & 1;                                           \
    if (kc + 1 == (C1)) {                                                     \
      asm volatile("s_waitcnt vmcnt(0)" ::: "memory");                        \
    } else {                                                                  \
      asm volatile("s_waitcnt vmcnt(12)" ::: "memory");                       \
    }                                                                         \
    __builtin_amdgcn_s_barrier();                                             \
    __builtin_amdgcn_sched_barrier(0);                                        \
    const bool active = (k0 <= q0 + 15);                                      \
    if (active) {                                                             \
      const char* Ksb = KsS + kb * 0;  /* placeholder, see below */           \
      (void)Ksb;                                                              \
    }                                                                         \
  }

// (CHUNK_LOOP macro unused; loop written inline in each kernel for clarity)

__global__ __launch_bounds__(256, 2)
void attn_plain(const short* __restrict__ Q, const short* __restrict__ K,
                const short* __restrict__ Vt, float* __restrict__ out) {
  ATTN_PRELUDE
  // NOTE: single shared K/V buffer pair per phase-shifted round-2 schedule.
  const int blk = blockIdx.x;
  const int qt = 31 - (blk >> 4);
  const int b  = blk & 15;
  const int q0 = qt * 64 + wave * 16;

  bf16x8 qf[12];
  const short* qp = Q + ((size_t)b * TT + q0 + l15) * CC + quad * 8;
  #pragma unroll
  for (int ks = 0; ks < 12; ++ks) qf[ks] = *(const bf16x8*)(qp + ks * 32);

  f32x4 o[24];
  #pragma unroll
  for (int n = 0; n < 24; ++n) o[n] = f32x4{0.f, 0.f, 0.f, 0.f};
  f32x4 lsum = f32x4{0.f, 0.f, 0.f, 0.f};
  float m[4];
  #pragma unroll
  for (int r = 0; r < 4; ++r) m[r] = -INFINITY;

  const char* kbB = (const char*)(K + (size_t)b * TT * CC);
  const char* vtB = (const char*)(Vt + (size_t)b * CC * TT);
  const int nchunk = qt * 2 + 2;

  STAGE_CHUNK(0);

  for (int kc = 0; kc < nchunk; ++kc) {
    const int k0 = kc * 32;
    asm volatile("s_waitcnt vmcnt(6)" ::: "memory");
    __builtin_amdgcn_s_barrier();
    __builtin_amdgcn_sched_barrier(0);

    f32x4 s0 = f32x4{0.f, 0.f, 0.f, 0.f};
    f32x4 s1 = f32x4{0.f, 0.f, 0.f, 0.f};
    const bool active = (k0 <= q0 + 15);
    if (active) {
      #pragma unroll
      for (int ks = 0; ks < 12; ++ks) {
        const int sl = (ks * 4 + quad) ^ (l15 & 7);
        const bf16x8 b0 = *(const bf16x8*)(KsS + l15 * 768 + (sl << 4));
        const bf16x8 b1 = *(const bf16x8*)(KsS + (16 + l15) * 768 + (sl << 4));
        s0 = __builtin_amdgcn_mfma_f32_16x16x32_bf16(qf[ks], b0, s0, 0, 0, 0);
        s1 = __builtin_amdgcn_mfma_f32_16x16x32_bf16(qf[ks], b1, s1, 0, 0, 0);
      }
    }
    __builtin_amdgcn_sched_barrier(0);
    __builtin_amdgcn_s_barrier();
    // issue K(kc+1)
    {
      const int kn = (kc + 1 < nchunk) ? (kc + 1) : kc;
      const size_t kby_ = (size_t)kn * 24576;
      #pragma unroll
      for (int j = 0; j < 6; ++j)
        __builtin_amdgcn_global_load_lds(
            (const __attribute__((address_space(1))) void*)(kbB + kby_ + koff[j]),
            (__attribute__((address_space(3))) void*)(KsW + j * 1024), 16, 0, 0);
    }
    asm volatile("s_waitcnt vmcnt(6)" ::: "memory");
    __builtin_amdgcn_s_barrier();
    __builtin_amdgcn_sched_barrier(0);

    if (active) {
      const bool domask = (k0 + 31 > q0);
      float mx[4];
      #pragma unroll
      for (int r = 0; r < 4; ++r) {
        float a = s0[r], c = s1[r];
        if (domask) {
          const int qg = q0 + quad * 4 + r;
          if (k0 + l15 > qg)      a = -INFINITY;
          if (k0 + 16 + l15 > qg) c = -INFINITY;
        }
        s0[r] = a; s1[r] = c;
        float v = fmaxf(a, c);
        v = fmaxf(v, __shfl_xor(v, 1));
        v = fmaxf(v, __shfl_xor(v, 2));
        v = fmaxf(v, __shfl_xor(v, 4));
        v = fmaxf(v, __shfl_xor(v, 8));
        mx[r] = v;
      }
      float alpha[4];
      #pragma unroll
      for (int r = 0; r < 4; ++r) {
        const float mn = fmaxf(m[r], mx[r]);
        alpha[r] = exp2f(m[r] - mn);
        m[r] = mn;
        s0[r] = exp2f(s0[r] - mn);
        s1[r] = exp2f(s1[r] - mn);
      }
      const bool need = (alpha[0] < 1.f) | (alpha[1] < 1.f) |
                        (alpha[2] < 1.f) | (alpha[3] < 1.f);
      if (__any(need)) {
        #pragma unroll
        for (int r = 0; r < 4; ++r) lsum[r] *= alpha[r];
        #pragma unroll
        for (int n = 0; n < 24; ++n) {
          #pragma unroll
          for (int r = 0; r < 4; ++r) o[n][r] *= alpha[r];
        }
      }
      #pragma unroll
      for (int r = 0; r < 4; ++r) {
        pw[(quad * 4 + r) * 40 + l15]      = f2bf(s0[r]);
        pw[(quad * 4 + r) * 40 + 16 + l15] = f2bf(s1[r]);
      }
      const bf16x8 pf = *(const bf16x8*)(pw + l15 * 40 + quad * 8);
      lsum = __builtin_amdgcn_mfma_f32_16x16x32_bf16(pf, onesf, lsum, 0, 0, 0);
      #pragma unroll
      for (int n = 0; n < 24; ++n) {
        const int vrow = n * 16 + l15;
        const bf16x8 vf = *(const bf16x8*)(VsS + vrow * 64 + (((quad + (vrow >> 2)) & 3) << 4));
        o[n] = __builtin_amdgcn_mfma_f32_16x16x32_bf16(pf, vf, o[n], 0, 0, 0);
      }
    }
    __builtin_amdgcn_sched_barrier(0);
    __builtin_amdgcn_s_barrier();
    // issue V(kc+1)
    {
      const int kn = (kc + 1 < nchunk) ? (kc + 1) : kc;
      const size_t vby_ = (size_t)kn * 64;
      #pragma unroll
      for (int j = 0; j < 6; ++j)
        __builtin_amdgcn_global_load_lds(
            (const __attribute__((address_space(1))) void*)(vtB + vby_ + voff[j]),
            (__attribute__((address_space(3))) void*)(VsW + j * 1024), 16, 0, 0);
    }
  }

  float linv[4];
  #pragma unroll
  for (int r = 0; r < 4; ++r) linv[r] = 1.f / lsum[r];
  float* ob = out + ((size_t)b * TT + q0) * CC;
  #pragma unroll
  for (int n = 0; n < 24; ++n) {
    #pragma unroll
    for (int r = 0; r < 4; ++r) {
      ob[(size_t)(quad * 4 + r) * CC + n * 16 + l15] = o[n][r] * linv[r];
    }
  }
}

__global__ __launch_bounds__(256, 2)
void attn_split(const short* __restrict__ Q, const short* __restrict__ K,
                const short* __restrict__ Vt, float* __restrict__ out,
                float* __restrict__ OB, float* __restrict__ ML) {
  ATTN_PRELUDE
  const int blk = blockIdx.x;
  const int b = blk & 15;                   // XCD = b%8
  const int s = blk >> 4;                   // 0..31
  const int j = s & 15;
  const int role = s >> 4;                  // 0=A, 1=B
  const int p = b * 16 + j;                 // pair id

  const char* kbB = (const char*)(K + (size_t)b * TT * CC);
  const char* vtB = (const char*)(Vt + (size_t)b * CC * TT);

  const int nph = role ? 1 : 2;
  #pragma unroll 1
  for (int ph = 0; ph < nph; ++ph) {
    int qt, c0, c1, mode;                   // mode: 0 final, 1 partA, 2 partB
    if (role == 0) {
      if (ph == 0) { qt = j;      c0 = 0;          c1 = 2 * j + 2;  mode = 0; }
      else         { qt = 31 - j; c0 = 0;          c1 = 31 - 2 * j; mode = 1; }
    } else         { qt = 31 - j; c0 = 31 - 2 * j; c1 = 64 - 2 * j; mode = 2; }
    const int q0 = qt * 64 + wave * 16;

    bf16x8 qf[12];
    const short* qp = Q + ((size_t)b * TT + q0 + l15) * CC + quad * 8;
    #pragma unroll
    for (int ks = 0; ks < 12; ++ks) qf[ks] = *(const bf16x8*)(qp + ks * 32);
    asm volatile("s_waitcnt vmcnt(0)" ::: "memory");   // drain q + prev stores

    f32x4 o[24];
    #pragma unroll
    for (int n = 0; n < 24; ++n) o[n] = f32x4{0.f, 0.f, 0.f, 0.f};
    f32x4 lsum = f32x4{0.f, 0.f, 0.f, 0.f};
    float m[4];
    #pragma unroll
    for (int r = 0; r < 4; ++r) m[r] = -INFINITY;

    // prologue: stage c0 -> buf0, c0+1 -> buf1 (buffers = K/V halves by kb)
    #pragma unroll 1
    for (int pc = 0; pc < 2; ++pc) {
      if (c0 + pc < c1) {
        char* KsWb = KsW + pc * 12288;      // NOTE: buffers interleave below
        (void)KsWb;
        const size_t kby_ = (size_t)(c0 + pc) * 24576;
        const size_t vby_ = (size_t)(c0 + pc) * 64;
        char* KW = KsS + pc * 12288 + wave * 3072;
        char* VW = VsS + pc * 12288 + wave * 3072;
        // each buffer is half-size: [32 keys][24 slots] K / [384 d][2 slots] V
        // -> use 3 issues of 1KB each for K and V per wave
        #pragma unroll
        for (int jj2 = 0; jj2 < 3; ++jj2) {
          const int lin = wave * 3072 + jj2 * 1024 + lane * 16;
          const int kr = lin / 384;
          const int ksl = (lin - kr * 384) >> 4;
          const int ko = kr * 768 + (((ksl * 2 + (jj2 & 0)) ^ 0) << 4); (void)ko;
          (void)kby_; (void)vby_; (void)KW; (void)VW; (void)lin; (void)kr; (void)ksl;
        }
      }
    }
    // --- The half-size buffer scheme above is wrong; use full double buffers
    // in the K/V regions directly (Ks buf = KsS + kb*12288 is too small).
    // Instead: alternate chunks between K-region and V-region is impossible;
    // so use single-buffer phase-shifted schedule identical to attn_plain,
    // restricted to [c0, c1). (Keeps LDS at 54272 and the proven pattern.)
    {
      const size_t kby0 = (size_t)c0 * 24576;
      const size_t vby0 = (size_t)c0 * 64;
      #pragma unroll
      for (int jj2 = 0; jj2 < 6; ++jj2)
        __builtin_amdgcn_global_load_lds(
            (const __attribute__((address_space(1))) void*)(kbB + kby0 + koff[jj2]),
            (__attribute__((address_space(3))) void*)(KsW + jj2 * 1024), 16, 0, 0);
      #pragma unroll
      for (int jj2 = 0; jj2 < 6; ++jj2)
        __builtin_amdgcn_global_load_lds(
            (const __attribute__((address_space(1))) void*)(vtB + vby0 + voff[jj2]),
            (__attribute__((address_space(3))) void*)(VsW + jj2 * 1024), 16, 0, 0);
    }

    #pragma unroll 1
    for (int kc = c0; kc < c1; ++kc) {
      const int k0 = kc * 32;
      asm volatile("s_waitcnt vmcnt(6)" ::: "memory");
      __builtin_amdgcn_s_barrier();
      __builtin_amdgcn_sched_barrier(0);

      f32x4 s0 = f32x4{0.f, 0.f, 0.f, 0.f};
      f32x4 s1 = f32x4{0.f, 0.f, 0.f, 0.f};
      const bool active = (k0 <= q0 + 15);
      if (active) {
        #pragma unroll
        for (int ks = 0; ks < 12; ++ks) {
          const int sl = (ks * 4 + quad) ^ (l15 & 7);
          const bf16x8 b0 = *(const bf16x8*)(KsS + l15 * 768 + (sl << 4));
          const bf16x8 b1 = *(const bf16x8*)(KsS + (16 + l15) * 768 + (sl << 4));
          s0 = __builtin_amdgcn_mfma_f32_16x16x32_bf16(qf[ks], b0, s0, 0, 0, 0);
          s1 = __builtin_amdgcn_mfma_f32_16x16x32_bf16(qf[ks], b1, s1, 0, 0, 0);
        }
      }
      __builtin_amdgcn_sched_barrier(0);
      __builtin_amdgcn_s_barrier();
      {
        const int kn = (kc + 1 < c1) ? (kc + 1) : kc;
        const size_t kby_ = (size_t)kn * 24576;
        #pragma unroll
        for (int jj2 = 0; jj2 < 6; ++jj2)
          __builtin_amdgcn_global_load_lds(
              (const __attribute__((address_space(1))) void*)(kbB + kby_ + koff[jj2]),
              (__attribute__((address_space(3))) void*)(KsW + jj2 * 1024), 16, 0, 0);
      }
      asm volatile("s_waitcnt vmcnt(6)" ::: "memory");
      __builtin_amdgcn_s_barrier();
      __builtin_amdgcn_sched_barrier(0);

      if (active) {
        const bool domask = (k0 + 31 > q0);
        float mx[4];
        #pragma unroll
        for (int r = 0; r < 4; ++r) {
          float a = s0[r], c = s1[r];
          if (domask) {
            const int qg = q0 + quad * 4 + r;
            if (k0 + l15 > qg)      a = -INFINITY;
            if (k0 + 16 + l15 > qg) c = -INFINITY;
          }
          s0[r] = a; s1[r] = c;
          float v = fmaxf(a, c);
          v = fmaxf(v, __shfl_xor(v, 1));
          v = fmaxf(v, __shfl_xor(v, 2));
          v = fmaxf(v, __shfl_xor(v, 4));
          v = fmaxf(v, __shfl_xor(v, 8));
          mx[r] = v;
        }
        float alpha[4];
        #pragma unroll
        for (int r = 0; r < 4; ++r) {
          const float mn = fmaxf(m[r], mx[r]);
          alpha[r] = exp2f(m[r] - mn);
          m[r] = mn;
          s0[r] = exp2f(s0[r] - mn);
          s1[r] = exp2f(s1[r] - mn);
        }
        const bool need = (alpha[0] < 1.f) | (alpha[1] < 1.f) |
                          (alpha[2] < 1.f) | (alpha[3] < 1.f);
        if (__any(need)) {
          #pragma unroll
          for (int r = 0; r < 4; ++r) lsum[r] *= alpha[r];
          #pragma unroll
          for (int n = 0; n < 24; ++n) {
            #pragma unroll
            for (int r = 0; r < 4; ++r) o[n][r] *= alpha[r];
          }
        }
        #pragma unroll
        for (int r = 0; r < 4; ++r) {
          pw[(quad * 4 + r) * 40 + l15]      = f2bf(s0[r]);
          pw[(quad * 4 + r) * 40 + 16 + l15] = f2bf(s1[r]);
        }
        const bf16x8 pf = *(const bf16x8*)(pw + l15 * 40 + quad * 8);
        lsum = __builtin_amdgcn_mfma_f32_16x16x32_bf16(pf, onesf, lsum, 0, 0, 0);
        #pragma unroll
        for (int n = 0; n < 24; ++n) {
          const int vrow = n * 16 + l15;
          const bf16x8 vf = *(const bf16x8*)(VsS + vrow * 64 + (((quad + (vrow >> 2)) & 3) << 4));
          o[n] = __builtin_amdgcn_mfma_f32_16x16x32_bf16(pf, vf, o[n], 0, 0, 0);
        }
      }
      __builtin_amdgcn_sched_barrier(0);
      __builtin_amdgcn_s_barrier();
      {
        const int kn = (kc + 1 < c1) ? (kc + 1) : kc;
        const size_t vby_ = (size_t)kn * 64;
        #pragma unroll
        for (int jj2 = 0; jj2 < 6; ++jj2)
          __builtin_amdgcn_global_load_lds(
              (const __attribute__((address_space(1))) void*)(vtB + vby_ + voff[jj2]),
              (__attribute__((address_space(3))) void*)(VsW + jj2 * 1024), 16, 0, 0);
      }
    }
    // drain the dummy re-stage of the last chunk before next phase/exit
    asm volatile("s_waitcnt vmcnt(0)" ::: "memory");
    __builtin_amdgcn_s_barrier();

    // ---- epilogue
    if (mode == 0) {
      float linv[4];
      #pragma unroll
      for (int r = 0; r < 4; ++r) linv[r] = 1.f / lsum[r];
      float* ob = out + ((size_t)b * TT + q0) * CC;
      #pragma unroll
      for (int n = 0; n < 24; ++n) {
        #pragma unroll
        for (int r = 0; r < 4; ++r)
          ob[(size_t)(quad * 4 + r) * CC + n * 16 + l15] = o[n][r] * linv[r];
      }
    } else {
      float* ob = (mode == 1)
          ? out + ((size_t)b * TT + q0) * CC
          : OB + (size_t)p * 24576 + (size_t)(wave * 16) * CC;
      #pragma unroll
      for (int n = 0; n < 24; ++n) {
        #pragma unroll
        for (int r = 0; r < 4; ++r)
          ob[(size_t)(quad * 4 + r) * CC + n * 16 + l15] = o[n][r];
      }
      if (l15 == 0) {
        float* pml = ML + (size_t)p * 256 + (mode - 1) * 128;
        #pragma unroll
        for (int r = 0; r < 4; ++r) {
          pml[(wave * 16 + quad * 4 + r) * 2]     = m[r];
          pml[(wave * 16 + quad * 4 + r) * 2 + 1] = lsum[r];
        }
      }
    }
  }
}

// ---------------------------------------------------------------------------
// Merge partial A (in out, unnormalized) with partial B (in ws) for the 256
// split H-tiles. 256 blocks x 256 threads; thread = (row, 96-col segment).
// ---------------------------------------------------------------------------
__global__ __launch_bounds__(256)
void combine(float* __restrict__ out, const float* __restrict__ OB,
             const float* __restrict__ ML) {
  const int p = blockIdx.x;
  const int b = p >> 4, j = p & 15;
  const int H = 31 - j;
  const int row = threadIdx.x >> 2, seg = threadIdx.x & 3;
  const float* ml = ML + (size_t)p * 256;
  const float mA = ml[row * 2],       lA = ml[row * 2 + 1];
  const float mB = ml[128 + row * 2], lB = ml[128 + row * 2 + 1];
  const float mF = fmaxf(mA, mB);
  const float sA = exp2f(mA - mF), sB = exp2f(mB - mF);
  const float inv = 1.f / (lA * sA + lB * sB);
  const float wA = sA * inv, wB = sB * inv;
  float* pa = out + ((size_t)b * TT + H * 64 + row) * CC + seg * 96;
  const float* pb = OB + (size_t)p * 24576 + (size_t)row * CC + seg * 96;
  #pragma unroll
  for (int c = 0; c < 24; ++c) {
    float4 a = *(float4*)(pa + c * 4);
    const float4 bb = *(const float4*)(pb + c * 4);
    a.x = a.x * wA + bb.x * wB;
    a.y = a.y * wA + bb.y * wB;
    a.z = a.z * wA + bb.z * wB;
    a.w = a.w * wA + bb.w * wB;
    *(float4*)(pa + c * 4) = a;
  }
}

extern "C" void kernel_launch(void* const* d_in, const int* in_sizes, int n_in,
                              void* d_out, int out_size, void* d_ws, size_t ws_size,
                              hipStream_t stream) {
  const float* x  = (const float*)d_in[0];
  const float* Wq = (const float*)d_in[1];
  const float* Wk = (const float*)d_in[2];
  const float* Wv = (const float*)d_in[3];
  float* out = (float*)d_out;

  const size_t QS = (size_t)NB * TT * CC;     // 12.58M elems
  short* Qs = (short*)d_ws;
  short* Ks = Qs + QS;
  short* Vt = Ks + QS;                        // 75,497,472 B

  const size_t base = QS * 3 * 2;
  float* OB = (float*)((char*)d_ws + base);             // 25,165,824 B
  float* ML = (float*)((char*)d_ws + base + 25165824);  //    524,288 B
  const bool split = ws_size >= base + 25165824 + 524288;

  // bf16 W^T (0.9MB) and bf16 x (25.2MB) staged in d_out until attn
  short* Wbt = (short*)d_out;
  short* xb  = (short*)((char*)d_out + 1048576);

  hipLaunchKernelGGL(conv_wt, dim3(3 * CC), dim3(CC), 0, stream, Wq, Wk, Wv, Wbt);
  hipLaunchKernelGGL(xconv, dim3(6144), dim3(256), 0, stream, x, xb);
  hipLaunchKernelGGL(proj_gemm, dim3(256 * 9), dim3(256), 0, stream,
                     xb, Wbt, Qs, Ks, Vt);
  if (split) {
    hipLaunchKernelGGL(attn_split, dim3(512), dim3(256), 0, stream,
                       Qs, Ks, Vt, out, OB, ML);
    hipLaunchKernelGGL(combine, dim3(256), dim3(256), 0, stream, out, OB, ML);
  } else {
    hipLaunchKernelGGL(attn_plain, dim3(512), dim3(256), 0, stream,
                       Qs, Ks, Vt, out);
  }
}